// Round 1
// baseline (1581.000 us; speedup 1.0000x reference)
//
#include <hip/hip_runtime.h>
#include <stdint.h>

// Problem constants (fixed by the reference)
#define M_DIM 8192    // 4*2048 rows of x
#define K_DIM 4096    // shared dim
#define N_DIM 11008   // output features

#define BM 128
#define BN 128
#define BK 64

// Harness dtype mapping (deduced from rounds 1-3 failure signatures):
//   x: float32 (fp16 upcast), w: int32 (int8 widened), s: float32, out: float32.

typedef __attribute__((ext_vector_type(8))) _Float16 half8;   // MFMA A/B fragment
typedef __attribute__((ext_vector_type(4))) _Float16 half4;
typedef __attribute__((ext_vector_type(4))) float floatx4;

// LDS XOR swizzle (T2): byte_off ^= (row&7)<<4  ==  half_idx ^= (row&7)<<3.
// Breaks the stride-128B slot-column conflict on ds_read_b128 fragment reads.
// Bijective within each row (XOR touches half-idx bits 3..5 only); preserves
// 8B alignment of half4 writes and 16B alignment of half8 reads/writes.
#define SWZ(row, col) ((col) ^ (((row) & 7) << 3))

// ---------------------------------------------------------------------------
// Kernel 1: dequantize q4_0 -> fp16 deq[N_DIM][K_DIM] in workspace.
// w row r (64 ints): msb nibbles -> deq[n=r/32][128*(r%32)+j], scale s[2r]
//                    lsb nibbles -> +64, scale s[2r+1].
// fp32 mul + single rounding to fp16 == reference's fp16 multiply (bit-exact).
// ---------------------------------------------------------------------------
__global__ __launch_bounds__(256) void dequant_q40(const int* __restrict__ w,
                                                   const float* __restrict__ s,
                                                   _Float16* __restrict__ deq) {
    int t = blockIdx.x * 256 + threadIdx.x;      // 352256*8 threads
    int r = t >> 3;                               // w row
    int j = (t & 7) * 8;                          // int offset in row
    const int* wp = w + (size_t)r * 64 + j;
    int4 p0 = *(const int4*)(wp);
    int4 p1 = *(const int4*)(wp + 4);
    float sm = s[2 * r];
    float sl = s[2 * r + 1];
    int n = r >> 5, u = r & 31;
    _Float16* dm = deq + (size_t)n * K_DIM + u * 128 + j;
    int v[8] = {p0.x, p0.y, p0.z, p0.w, p1.x, p1.y, p1.z, p1.w};
    half8 vm, vl;
#pragma unroll
    for (int i = 0; i < 8; ++i) {
        int b = v[i];                             // original int8 value, widened
        vm[i] = (_Float16)((float)(b >> 4) * sm);          // arithmetic msb
        vl[i] = (_Float16)((float)((b << 28) >> 28) * sl); // sign-extended lsb
    }
    *(half8*)dm = vm;
    *(half8*)(dm + 64) = vl;
}

// ---------------------------------------------------------------------------
// Kernel 2: gemm_bt, explicit staging. C[M][N] = A[M][K] * deq[N][K]^T.
// A fp32 (converted to fp16 during staging), B fp16 (prepass), C fp32.
// 128x128 tile, BK=64, 4 waves (2x2), wave = 64x64 via 4x4 mfma 16x16x32 f16.
// LDS tiles XOR-swizzled (T2) to kill the stride-128B bank conflicts.
// ---------------------------------------------------------------------------
__global__ __launch_bounds__(256, 2) void gemm_f16_bt(const float* __restrict__ A,
                                                      const _Float16* __restrict__ B,
                                                      float* __restrict__ C) {
    __shared__ _Float16 As[BM * BK];   // [128][64] row-major fp16, swizzled
    __shared__ _Float16 Bs[BN * BK];

    const int tid  = threadIdx.x;
    const int lane = tid & 63;
    const int wave = tid >> 6;
    const int wm = (wave >> 1) * 64;
    const int wn = (wave & 1) * 64;
    const int m0 = blockIdx.y * BM;
    const int n0 = blockIdx.x * BN;

    floatx4 acc[4][4] = {};
    const int lrow = lane & 15;        // fragment row index (m or n)
    const int quad = lane >> 4;        // k sub-offset selector
    const int kxor = (lrow & 7) << 3;  // fragment-read swizzle (row&7 == lrow&7)

    for (int kk = 0; kk < K_DIM; kk += BK) {
        // ---- A tile: 128x64 fp32 = 8192 floats; 8 x (256 thr x float4)
        float4 av[8];
#pragma unroll
        for (int i = 0; i < 8; ++i) {
            int flat = i * 256 + tid;          // [0,2048)
            int row = flat >> 4;               // 16 threads/row, 4 floats each
            int col = (flat & 15) * 4;
            av[i] = *(const float4*)(A + (size_t)(m0 + row) * K_DIM + kk + col);
        }
        // ---- B tile: 128x64 fp16 = 8192 halfs; 4 x (256 thr x half8)
        half8 bv[4];
#pragma unroll
        for (int i = 0; i < 4; ++i) {
            int flat = i * 256 + tid;          // [0,1024)
            int row = flat >> 3;               // 8 threads/row, 8 halfs each
            int col = (flat & 7) * 8;
            bv[i] = *(const half8*)(B + (size_t)(n0 + row) * K_DIM + kk + col);
        }
        __syncthreads();   // prior iteration's LDS reads done before overwrite
#pragma unroll
        for (int i = 0; i < 8; ++i) {
            int flat = i * 256 + tid;
            int row = flat >> 4;
            int col = (flat & 15) * 4;
            half4 a16;
            a16[0] = (_Float16)av[i].x;        // lossless: x values are fp16-exact
            a16[1] = (_Float16)av[i].y;
            a16[2] = (_Float16)av[i].z;
            a16[3] = (_Float16)av[i].w;
            *(half4*)(As + row * BK + SWZ(row, col)) = a16;
        }
#pragma unroll
        for (int i = 0; i < 4; ++i) {
            int flat = i * 256 + tid;
            int row = flat >> 3;
            int col = (flat & 7) * 8;
            *(half8*)(Bs + row * BK + SWZ(row, col)) = bv[i];
        }
        __syncthreads();   // tiles visible to all waves

        // ---- compute: 2 k-iters of 32, 16 MFMAs each
#pragma unroll
        for (int ks = 0; ks < BK; ks += 32) {
            int koff = (ks + quad * 8) ^ kxor;   // swizzled fragment column
            half8 af[4], bf[4];
#pragma unroll
            for (int im = 0; im < 4; ++im)
                af[im] = *(const half8*)(As + (wm + im * 16 + lrow) * BK + koff);
#pragma unroll
            for (int in_ = 0; in_ < 4; ++in_)
                bf[in_] = *(const half8*)(Bs + (wn + in_ * 16 + lrow) * BK + koff);
#pragma unroll
            for (int im = 0; im < 4; ++im)
#pragma unroll
                for (int in_ = 0; in_ < 4; ++in_)
                    acc[im][in_] = __builtin_amdgcn_mfma_f32_16x16x32_f16(
                        af[im], bf[in_], acc[im][in_], 0, 0, 0);
        }
    }

    // ---- epilogue: C/D layout col=lane&15, row=(lane>>4)*4+reg; fp32 stores
#pragma unroll
    for (int im = 0; im < 4; ++im) {
#pragma unroll
        for (int in_ = 0; in_ < 4; ++in_) {
            int col = n0 + wn + in_ * 16 + lrow;
#pragma unroll
            for (int r = 0; r < 4; ++r) {
                int row = m0 + wm + im * 16 + quad * 4 + r;
                C[(size_t)row * N_DIM + col] = acc[im][in_][r];
            }
        }
    }
}

// ---------------------------------------------------------------------------
// Fallback: fused dequant-in-GEMM (only if ws too small for the deq prepass).
// Same swizzle applied for consistency (not exercised when ws fits).
// ---------------------------------------------------------------------------
__global__ __launch_bounds__(256, 2) void gemm_fused(const float* __restrict__ A,
                                                     const int* __restrict__ W,
                                                     const float* __restrict__ S,
                                                     float* __restrict__ C) {
    __shared__ _Float16 As[BM * BK];
    __shared__ _Float16 Bs[BN * BK];

    const int tid  = threadIdx.x;
    const int lane = tid & 63;
    const int wave = tid >> 6;
    const int wm = (wave >> 1) * 64;
    const int wn = (wave & 1) * 64;
    const int m0 = blockIdx.y * BM;
    const int n0 = blockIdx.x * BN;

    floatx4 acc[4][4] = {};
    const int lrow = lane & 15;
    const int quad = lane >> 4;
    const int kxor = (lrow & 7) << 3;

    const int nn = tid >> 1;           // n-row handled by this thread (pairwise)
    const int bh = (tid & 1) * 32;     // which half of the 64-wide k-group

    for (int kk = 0; kk < K_DIM; kk += BK) {
        float4 av[8];
#pragma unroll
        for (int i = 0; i < 8; ++i) {
            int flat = i * 256 + tid;
            int row = flat >> 4;
            int col = (flat & 15) * 4;
            av[i] = *(const float4*)(A + (size_t)(m0 + row) * K_DIM + kk + col);
        }
        // B: dequant 32 ints -> 32 fp16 per thread, covering Bs[nn][bh..bh+31]
        int t64 = kk >> 6;             // scale-group index along k
        int u = t64 >> 1;              // w sub-row
        const int* wr = W + ((size_t)(n0 + nn) * 32 + u) * 64 + bh;
        float sc = S[(size_t)(n0 + nn) * 64 + t64];
        bool sel_lsb = (t64 & 1);
        half8 bq[4];
#pragma unroll
        for (int i8 = 0; i8 < 4; ++i8) {
            int4 pa = *(const int4*)(wr + i8 * 8);
            int4 pb = *(const int4*)(wr + i8 * 8 + 4);
            int vv[8] = {pa.x, pa.y, pa.z, pa.w, pb.x, pb.y, pb.z, pb.w};
#pragma unroll
            for (int q = 0; q < 8; ++q) {
                int b = vv[q];
                int qq = sel_lsb ? ((b << 28) >> 28) : (b >> 4);
                bq[i8][q] = (_Float16)((float)qq * sc);
            }
        }
        __syncthreads();
#pragma unroll
        for (int i = 0; i < 8; ++i) {
            int flat = i * 256 + tid;
            int row = flat >> 4;
            int col = (flat & 15) * 4;
            half4 a16;
            a16[0] = (_Float16)av[i].x;
            a16[1] = (_Float16)av[i].y;
            a16[2] = (_Float16)av[i].z;
            a16[3] = (_Float16)av[i].w;
            *(half4*)(As + row * BK + SWZ(row, col)) = a16;
        }
#pragma unroll
        for (int i8 = 0; i8 < 4; ++i8)
            *(half8*)(Bs + nn * BK + SWZ(nn, bh + i8 * 8)) = bq[i8];
        __syncthreads();

#pragma unroll
        for (int ks = 0; ks < BK; ks += 32) {
            int koff = (ks + quad * 8) ^ kxor;
            half8 af[4], bf[4];
#pragma unroll
            for (int im = 0; im < 4; ++im)
                af[im] = *(const half8*)(As + (wm + im * 16 + lrow) * BK + koff);
#pragma unroll
            for (int in_ = 0; in_ < 4; ++in_)
                bf[in_] = *(const half8*)(Bs + (wn + in_ * 16 + lrow) * BK + koff);
#pragma unroll
            for (int im = 0; im < 4; ++im)
#pragma unroll
                for (int in_ = 0; in_ < 4; ++in_)
                    acc[im][in_] = __builtin_amdgcn_mfma_f32_16x16x32_f16(
                        af[im], bf[in_], acc[im][in_], 0, 0, 0);
        }
    }

#pragma unroll
    for (int im = 0; im < 4; ++im) {
#pragma unroll
        for (int in_ = 0; in_ < 4; ++in_) {
            int col = n0 + wn + in_ * 16 + lrow;
#pragma unroll
            for (int r = 0; r < 4; ++r) {
                int row = m0 + wm + im * 16 + quad * 4 + r;
                C[(size_t)row * N_DIM + col] = acc[im][in_][r];
            }
        }
    }
}

extern "C" void kernel_launch(void* const* d_in, const int* in_sizes, int n_in,
                              void* d_out, int out_size, void* d_ws, size_t ws_size,
                              hipStream_t stream) {
    const float* x = (const float*)d_in[0];   // fp16 upcast to fp32 by harness
    const int*   w = (const int*)d_in[1];     // int8 widened to int32
    const float* s = (const float*)d_in[2];   // fp16 upcast to fp32
    float*     out = (float*)d_out;           // fp32

    const size_t deq_bytes = (size_t)N_DIM * K_DIM * sizeof(_Float16); // 90.2 MB
    dim3 grid(N_DIM / BN, M_DIM / BM);   // 86 x 64 = 5504 blocks

    if (ws_size >= deq_bytes) {
        _Float16* deq = (_Float16*)d_ws;
        dequant_q40<<<11008, 256, 0, stream>>>(w, s, deq);
        gemm_f16_bt<<<grid, 256, 0, stream>>>(x, deq, out);
    } else {
        gemm_fused<<<grid, 256, 0, stream>>>(x, w, s, out);
    }
}

// Round 2
// 1323.760 us; speedup vs baseline: 1.1943x; 1.1943x over previous
//
#include <hip/hip_runtime.h>
#include <stdint.h>

// Problem constants (fixed by the reference)
#define M_DIM 8192    // 4*2048 rows of x
#define K_DIM 4096    // shared dim
#define N_DIM 11008   // output features

#define BM 128
#define BN 128
#define BK 64

// Harness dtype mapping: x fp32 (fp16 upcast), w int32 (int8 widened),
// s fp32, out fp32.

typedef __attribute__((ext_vector_type(8))) _Float16 half8;   // MFMA A/B fragment
typedef __attribute__((ext_vector_type(4))) _Float16 half4;
typedef __attribute__((ext_vector_type(4))) float floatx4;

// LDS XOR swizzle (T2): half_idx ^= (row&7)<<3 (byte ^= (row&7)<<4).
#define SWZ(row, col) ((col) ^ (((row) & 7) << 3))

// global -> LDS direct (DMA) load, 16 B per lane. LDS dest must be the
// wave-uniform base; HW adds lane*16. Global src is per-lane (lets us
// inverse-swizzle the source so swizzled reads see linear data: rule #21).
#define GLD_LDS16(gp, lp)                                                     \
    __builtin_amdgcn_global_load_lds(                                         \
        (const __attribute__((address_space(1))) uint32_t*)(gp),              \
        (__attribute__((address_space(3))) uint32_t*)(lp), 16, 0, 0)

// ---------------------------------------------------------------------------
// Kernel 1: dequantize q4_0 -> fp16 deq[N_DIM][K_DIM] in workspace.
// fp32 mul + single rounding to fp16 == reference's fp16 multiply (bit-exact).
// ---------------------------------------------------------------------------
__global__ __launch_bounds__(256) void dequant_q40(const int* __restrict__ w,
                                                   const float* __restrict__ s,
                                                   _Float16* __restrict__ deq) {
    int t = blockIdx.x * 256 + threadIdx.x;
    int r = t >> 3;                               // w row
    int j = (t & 7) * 8;                          // int offset in row
    const int* wp = w + (size_t)r * 64 + j;
    int4 p0 = *(const int4*)(wp);
    int4 p1 = *(const int4*)(wp + 4);
    float sm = s[2 * r];
    float sl = s[2 * r + 1];
    int n = r >> 5, u = r & 31;
    _Float16* dm = deq + (size_t)n * K_DIM + u * 128 + j;
    int v[8] = {p0.x, p0.y, p0.z, p0.w, p1.x, p1.y, p1.z, p1.w};
    half8 vm, vl;
#pragma unroll
    for (int i = 0; i < 8; ++i) {
        int b = v[i];
        vm[i] = (_Float16)((float)(b >> 4) * sm);          // arithmetic msb
        vl[i] = (_Float16)((float)((b << 28) >> 28) * sl); // sign-extended lsb
    }
    *(half8*)dm = vm;
    *(half8*)(dm + 64) = vl;
}

// ---------------------------------------------------------------------------
// Kernel 1b: A fp32 -> fp16 copy (lossless: x was fp16 upcast by harness).
// Enables global_load_lds staging of A in the GEMM. 8 elems/thread.
// ---------------------------------------------------------------------------
__global__ __launch_bounds__(256) void conv_a16(const float* __restrict__ A,
                                                _Float16* __restrict__ A16) {
    size_t t = (size_t)blockIdx.x * 256 + threadIdx.x;
    const float* p = A + t * 8;
    float4 v0 = *(const float4*)(p);
    float4 v1 = *(const float4*)(p + 4);
    half8 h;
    h[0] = (_Float16)v0.x; h[1] = (_Float16)v0.y;
    h[2] = (_Float16)v0.z; h[3] = (_Float16)v0.w;
    h[4] = (_Float16)v1.x; h[5] = (_Float16)v1.y;
    h[6] = (_Float16)v1.z; h[7] = (_Float16)v1.w;
    *(half8*)(A16 + t * 8) = h;
}

// ---------------------------------------------------------------------------
// Kernel 2 (fast path): C[M][N] = A16[M][K] * deq[N][K]^T, both fp16.
// m97 structure: global_load_lds width-16 staging, 2-barrier K-loop,
// 128x128 tile / BK=64 / 4 waves / 4x4 mfma 16x16x32 f16 per wave.
// LDS stays conflict-free: linear DMA dest + inverse-swizzled global src
// + swizzled ds_read (the source and read permutations are the same
// involution, so reads see logically-linear data).
// ---------------------------------------------------------------------------
__global__ __launch_bounds__(256, 2) void gemm_lds16(const _Float16* __restrict__ A,
                                                     const _Float16* __restrict__ B,
                                                     float* __restrict__ C) {
    __shared__ _Float16 As[BM * BK];   // [128][64] halfs, swizzled content
    __shared__ _Float16 Bs[BN * BK];

    const int tid  = threadIdx.x;
    const int lane = tid & 63;
    const int wave = tid >> 6;
    const int wm = (wave >> 1) * 64;
    const int wn = (wave & 1) * 64;

    // XCD-aware bijective block swizzle (nwg = 5504, divisible by 8).
    const int nwg_per_xcd = (N_DIM / BN) * (M_DIM / BM) / 8;   // 688
    int bid = blockIdx.x;
    int swz = (bid & 7) * nwg_per_xcd + (bid >> 3);
    const int n0 = (swz % (N_DIM / BN)) * BN;
    const int m0 = (swz / (N_DIM / BN)) * BM;

    // Staging geometry: wave w stages rows [w*32, w*32+32) of both tiles,
    // as 4 loads of 1 KB (8 rows x 128 B). Lane l covers local row l>>3,
    // 16 B at col (l&7)*16. Inverse-swizzle source col: since row&7 == l>>3
    // for every load, the source column is a per-lane CONSTANT.
    const int lrow8 = lane >> 3;                        // 0..7
    const int lcol  = ((lane & 7) * 8) ^ (lrow8 << 3);  // halfs, pre-swizzled

    const _Float16* aptr = A + (size_t)(m0 + wave * 32 + lrow8) * K_DIM + lcol;
    const _Float16* bptr = B + (size_t)(n0 + wave * 32 + lrow8) * K_DIM + lcol;
    _Float16* asl = As + (wave * 32) * BK;   // wave-uniform LDS bases
    _Float16* bsl = Bs + (wave * 32) * BK;

    floatx4 acc[4][4] = {};
    const int lrow = lane & 15;        // fragment row index (m or n)
    const int quad = lane >> 4;        // k sub-offset selector
    const int kxor = (lrow & 7) << 3;  // fragment-read swizzle

    for (int kk = 0; kk < K_DIM; kk += BK) {
        __syncthreads();   // prior iteration's LDS reads done before DMA overwrite
#pragma unroll
        for (int i = 0; i < 4; ++i)
            GLD_LDS16(aptr + (size_t)(i * 8) * K_DIM + kk, asl + i * 8 * BK);
#pragma unroll
        for (int i = 0; i < 4; ++i)
            GLD_LDS16(bptr + (size_t)(i * 8) * K_DIM + kk, bsl + i * 8 * BK);
        __syncthreads();   // drains vmcnt(0): tiles visible to all waves

#pragma unroll
        for (int ks = 0; ks < BK; ks += 32) {
            int koff = (ks + quad * 8) ^ kxor;   // swizzled fragment column
            half8 af[4], bf[4];
#pragma unroll
            for (int im = 0; im < 4; ++im)
                af[im] = *(const half8*)(As + (wm + im * 16 + lrow) * BK + koff);
#pragma unroll
            for (int in_ = 0; in_ < 4; ++in_)
                bf[in_] = *(const half8*)(Bs + (wn + in_ * 16 + lrow) * BK + koff);
#pragma unroll
            for (int im = 0; im < 4; ++im)
#pragma unroll
                for (int in_ = 0; in_ < 4; ++in_)
                    acc[im][in_] = __builtin_amdgcn_mfma_f32_16x16x32_f16(
                        af[im], bf[in_], acc[im][in_], 0, 0, 0);
        }
    }

    // ---- epilogue: C/D layout col=lane&15, row=(lane>>4)*4+reg; fp32 stores
#pragma unroll
    for (int im = 0; im < 4; ++im) {
#pragma unroll
        for (int in_ = 0; in_ < 4; ++in_) {
            int col = n0 + wn + in_ * 16 + lrow;
#pragma unroll
            for (int r = 0; r < 4; ++r) {
                int row = m0 + wm + im * 16 + quad * 4 + r;
                C[(size_t)row * N_DIM + col] = acc[im][in_][r];
            }
        }
    }
}

// ---------------------------------------------------------------------------
// Mid path (ws fits deq only): explicit-staging GEMM from round 1.
// ---------------------------------------------------------------------------
__global__ __launch_bounds__(256, 2) void gemm_f16_bt(const float* __restrict__ A,
                                                      const _Float16* __restrict__ B,
                                                      float* __restrict__ C) {
    __shared__ _Float16 As[BM * BK];
    __shared__ _Float16 Bs[BN * BK];

    const int tid  = threadIdx.x;
    const int lane = tid & 63;
    const int wave = tid >> 6;
    const int wm = (wave >> 1) * 64;
    const int wn = (wave & 1) * 64;
    const int m0 = blockIdx.y * BM;
    const int n0 = blockIdx.x * BN;

    floatx4 acc[4][4] = {};
    const int lrow = lane & 15;
    const int quad = lane >> 4;
    const int kxor = (lrow & 7) << 3;

    for (int kk = 0; kk < K_DIM; kk += BK) {
        float4 av[8];
#pragma unroll
        for (int i = 0; i < 8; ++i) {
            int flat = i * 256 + tid;
            int row = flat >> 4;
            int col = (flat & 15) * 4;
            av[i] = *(const float4*)(A + (size_t)(m0 + row) * K_DIM + kk + col);
        }
        half8 bv[4];
#pragma unroll
        for (int i = 0; i < 4; ++i) {
            int flat = i * 256 + tid;
            int row = flat >> 3;
            int col = (flat & 7) * 8;
            bv[i] = *(const half8*)(B + (size_t)(n0 + row) * K_DIM + kk + col);
        }
        __syncthreads();
#pragma unroll
        for (int i = 0; i < 8; ++i) {
            int flat = i * 256 + tid;
            int row = flat >> 4;
            int col = (flat & 15) * 4;
            half4 a16;
            a16[0] = (_Float16)av[i].x;
            a16[1] = (_Float16)av[i].y;
            a16[2] = (_Float16)av[i].z;
            a16[3] = (_Float16)av[i].w;
            *(half4*)(As + row * BK + SWZ(row, col)) = a16;
        }
#pragma unroll
        for (int i = 0; i < 4; ++i) {
            int flat = i * 256 + tid;
            int row = flat >> 3;
            int col = (flat & 7) * 8;
            *(half8*)(Bs + row * BK + SWZ(row, col)) = bv[i];
        }
        __syncthreads();

#pragma unroll
        for (int ks = 0; ks < BK; ks += 32) {
            int koff = (ks + quad * 8) ^ kxor;
            half8 af[4], bf[4];
#pragma unroll
            for (int im = 0; im < 4; ++im)
                af[im] = *(const half8*)(As + (wm + im * 16 + lrow) * BK + koff);
#pragma unroll
            for (int in_ = 0; in_ < 4; ++in_)
                bf[in_] = *(const half8*)(Bs + (wn + in_ * 16 + lrow) * BK + koff);
#pragma unroll
            for (int im = 0; im < 4; ++im)
#pragma unroll
                for (int in_ = 0; in_ < 4; ++in_)
                    acc[im][in_] = __builtin_amdgcn_mfma_f32_16x16x32_f16(
                        af[im], bf[in_], acc[im][in_], 0, 0, 0);
        }
    }

#pragma unroll
    for (int im = 0; im < 4; ++im) {
#pragma unroll
        for (int in_ = 0; in_ < 4; ++in_) {
            int col = n0 + wn + in_ * 16 + lrow;
#pragma unroll
            for (int r = 0; r < 4; ++r) {
                int row = m0 + wm + im * 16 + quad * 4 + r;
                C[(size_t)row * N_DIM + col] = acc[im][in_][r];
            }
        }
    }
}

// ---------------------------------------------------------------------------
// Fallback: fused dequant-in-GEMM (only if ws too small for any prepass).
// ---------------------------------------------------------------------------
__global__ __launch_bounds__(256, 2) void gemm_fused(const float* __restrict__ A,
                                                     const int* __restrict__ W,
                                                     const float* __restrict__ S,
                                                     float* __restrict__ C) {
    __shared__ _Float16 As[BM * BK];
    __shared__ _Float16 Bs[BN * BK];

    const int tid  = threadIdx.x;
    const int lane = tid & 63;
    const int wave = tid >> 6;
    const int wm = (wave >> 1) * 64;
    const int wn = (wave & 1) * 64;
    const int m0 = blockIdx.y * BM;
    const int n0 = blockIdx.x * BN;

    floatx4 acc[4][4] = {};
    const int lrow = lane & 15;
    const int quad = lane >> 4;
    const int kxor = (lrow & 7) << 3;

    const int nn = tid >> 1;
    const int bh = (tid & 1) * 32;

    for (int kk = 0; kk < K_DIM; kk += BK) {
        float4 av[8];
#pragma unroll
        for (int i = 0; i < 8; ++i) {
            int flat = i * 256 + tid;
            int row = flat >> 4;
            int col = (flat & 15) * 4;
            av[i] = *(const float4*)(A + (size_t)(m0 + row) * K_DIM + kk + col);
        }
        int t64 = kk >> 6;
        int u = t64 >> 1;
        const int* wr = W + ((size_t)(n0 + nn) * 32 + u) * 64 + bh;
        float sc = S[(size_t)(n0 + nn) * 64 + t64];
        bool sel_lsb = (t64 & 1);
        half8 bq[4];
#pragma unroll
        for (int i8 = 0; i8 < 4; ++i8) {
            int4 pa = *(const int4*)(wr + i8 * 8);
            int4 pb = *(const int4*)(wr + i8 * 8 + 4);
            int vv[8] = {pa.x, pa.y, pa.z, pa.w, pb.x, pb.y, pb.z, pb.w};
#pragma unroll
            for (int q = 0; q < 8; ++q) {
                int b = vv[q];
                int qq = sel_lsb ? ((b << 28) >> 28) : (b >> 4);
                bq[i8][q] = (_Float16)((float)qq * sc);
            }
        }
        __syncthreads();
#pragma unroll
        for (int i = 0; i < 8; ++i) {
            int flat = i * 256 + tid;
            int row = flat >> 4;
            int col = (flat & 15) * 4;
            half4 a16;
            a16[0] = (_Float16)av[i].x;
            a16[1] = (_Float16)av[i].y;
            a16[2] = (_Float16)av[i].z;
            a16[3] = (_Float16)av[i].w;
            *(half4*)(As + row * BK + SWZ(row, col)) = a16;
        }
#pragma unroll
        for (int i8 = 0; i8 < 4; ++i8)
            *(half8*)(Bs + nn * BK + SWZ(nn, bh + i8 * 8)) = bq[i8];
        __syncthreads();

#pragma unroll
        for (int ks = 0; ks < BK; ks += 32) {
            int koff = (ks + quad * 8) ^ kxor;
            half8 af[4], bf[4];
#pragma unroll
            for (int im = 0; im < 4; ++im)
                af[im] = *(const half8*)(As + (wm + im * 16 + lrow) * BK + koff);
#pragma unroll
            for (int in_ = 0; in_ < 4; ++in_)
                bf[in_] = *(const half8*)(Bs + (wn + in_ * 16 + lrow) * BK + koff);
#pragma unroll
            for (int im = 0; im < 4; ++im)
#pragma unroll
                for (int in_ = 0; in_ < 4; ++in_)
                    acc[im][in_] = __builtin_amdgcn_mfma_f32_16x16x32_f16(
                        af[im], bf[in_], acc[im][in_], 0, 0, 0);
        }
    }

#pragma unroll
    for (int im = 0; im < 4; ++im) {
#pragma unroll
        for (int in_ = 0; in_ < 4; ++in_) {
            int col = n0 + wn + in_ * 16 + lrow;
#pragma unroll
            for (int r = 0; r < 4; ++r) {
                int row = m0 + wm + im * 16 + quad * 4 + r;
                C[(size_t)row * N_DIM + col] = acc[im][in_][r];
            }
        }
    }
}

extern "C" void kernel_launch(void* const* d_in, const int* in_sizes, int n_in,
                              void* d_out, int out_size, void* d_ws, size_t ws_size,
                              hipStream_t stream) {
    const float* x = (const float*)d_in[0];   // fp16 upcast to fp32 by harness
    const int*   w = (const int*)d_in[1];     // int8 widened to int32
    const float* s = (const float*)d_in[2];   // fp16 upcast to fp32
    float*     out = (float*)d_out;           // fp32

    const size_t deq_bytes = (size_t)N_DIM * K_DIM * sizeof(_Float16); // 90.2 MB
    const size_t a16_bytes = (size_t)M_DIM * K_DIM * sizeof(_Float16); // 67.1 MB

    if (ws_size >= deq_bytes + a16_bytes) {
        _Float16* deq = (_Float16*)d_ws;
        _Float16* a16 = (_Float16*)((char*)d_ws + deq_bytes);
        dequant_q40<<<11008, 256, 0, stream>>>(w, s, deq);
        conv_a16<<<(M_DIM * K_DIM / 8) / 256, 256, 0, stream>>>(x, a16);
        gemm_lds16<<<(N_DIM / BN) * (M_DIM / BM), 256, 0, stream>>>(a16, deq, out);
    } else if (ws_size >= deq_bytes) {
        _Float16* deq = (_Float16*)d_ws;
        dim3 grid(N_DIM / BN, M_DIM / BM);
        dequant_q40<<<11008, 256, 0, stream>>>(w, s, deq);
        gemm_f16_bt<<<grid, 256, 0, stream>>>(x, deq, out);
    } else {
        dim3 grid(N_DIM / BN, M_DIM / BM);
        gemm_fused<<<grid, 256, 0, stream>>>(x, w, s, out);
    }
}

// Round 5
// 1305.383 us; speedup vs baseline: 1.2111x; 1.0141x over previous
//
#include <hip/hip_runtime.h>
#include <stdint.h>

// Problem constants (fixed by the reference)
#define M_DIM 8192    // 4*2048 rows of x
#define K_DIM 4096    // shared dim
#define N_DIM 11008   // output features

// 8-phase GEMM geometry
#define BM2 256
#define BN2 256
#define BK2 64
#define TILE_H (256 * 64)   // halfs per LDS buffer per matrix (32 KB)
#define NT (K_DIM / BK2)    // 64 K-tiles

// fallback geometry
#define BM 128
#define BN 128
#define BK 64

// Harness dtype mapping: x fp32 (fp16 upcast), w int32 (int8 widened),
// s fp32, out fp32.

typedef __attribute__((ext_vector_type(8))) _Float16 half8;
typedef __attribute__((ext_vector_type(4))) _Float16 half4;
typedef __attribute__((ext_vector_type(4))) float floatx4;

// LDS XOR swizzle (T2): half_idx ^= (row&7)<<3 (byte ^= (row&7)<<4).
// Proven zero-conflict on the 16-row x 4-quad ds_read_b128 fragment pattern
// (rounds 1-2: SQ_LDS_BANK_CONFLICT == 0).
#define SWZ(row, col) ((col) ^ (((row) & 7) << 3))

// global -> LDS direct (DMA) load, 16 B per lane. LDS dest = wave-uniform
// base (+lane*16 by HW). Global src is per-lane -> inverse-swizzled source
// keeps LDS reads conflict-free (rule #21: both-sides-or-neither).
#define GLD_LDS16(gp, lp)                                                     \
    __builtin_amdgcn_global_load_lds(                                         \
        (const __attribute__((address_space(1))) uint32_t*)(gp),              \
        (__attribute__((address_space(3))) uint32_t*)(lp), 16, 0, 0)

// ---------------------------------------------------------------------------
// Kernel 1: dequantize q4_0 -> fp16 deq[N_DIM][K_DIM] in workspace.
// fp32 mul + single rounding to fp16 == reference's fp16 multiply (bit-exact).
// ---------------------------------------------------------------------------
__global__ __launch_bounds__(256) void dequant_q40(const int* __restrict__ w,
                                                   const float* __restrict__ s,
                                                   _Float16* __restrict__ deq) {
    int t = blockIdx.x * 256 + threadIdx.x;
    int r = t >> 3;                               // w row
    int j = (t & 7) * 8;                          // int offset in row
    const int* wp = w + (size_t)r * 64 + j;
    int4 p0 = *(const int4*)(wp);
    int4 p1 = *(const int4*)(wp + 4);
    float sm = s[2 * r];
    float sl = s[2 * r + 1];
    int n = r >> 5, u = r & 31;
    _Float16* dm = deq + (size_t)n * K_DIM + u * 128 + j;
    int v[8] = {p0.x, p0.y, p0.z, p0.w, p1.x, p1.y, p1.z, p1.w};
    half8 vm, vl;
#pragma unroll
    for (int i = 0; i < 8; ++i) {
        int b = v[i];
        vm[i] = (_Float16)((float)(b >> 4) * sm);          // arithmetic msb
        vl[i] = (_Float16)((float)((b << 28) >> 28) * sl); // sign-extended lsb
    }
    *(half8*)dm = vm;
    *(half8*)(dm + 64) = vl;
}

// ---------------------------------------------------------------------------
// Kernel 1b: A fp32 -> fp16 copy (lossless: x was fp16 upcast by harness).
// ---------------------------------------------------------------------------
__global__ __launch_bounds__(256) void conv_a16(const float* __restrict__ A,
                                                _Float16* __restrict__ A16) {
    size_t t = (size_t)blockIdx.x * 256 + threadIdx.x;
    const float* p = A + t * 8;
    float4 v0 = *(const float4*)(p);
    float4 v1 = *(const float4*)(p + 4);
    half8 h;
    h[0] = (_Float16)v0.x; h[1] = (_Float16)v0.y;
    h[2] = (_Float16)v0.z; h[3] = (_Float16)v0.w;
    h[4] = (_Float16)v1.x; h[5] = (_Float16)v1.y;
    h[6] = (_Float16)v1.z; h[7] = (_Float16)v1.w;
    *(half8*)(A16 + t * 8) = h;
}

// ---------------------------------------------------------------------------
// Kernel 2 (fast path): 8-phase 256x256 GEMM (T2+T3+T4+T5).
// C[M][N] = A16[M][K] * deq[N][K]^T, both fp16, C fp32.
// 512 thr = 8 waves (2M x 4N); wave output 128x64 = acc[8][4] 16x16 frags.
// LDS: A,B double-buffered [256][64] fp16 = 128 KiB, XOR-swizzled content
// (linear DMA dest + inverse-swizzled global source + swizzled ds_read).
//
// RACE FIX (round 4 post-mortem): every barrier is inline asm with a
// "memory" clobber. The bare __builtin_amdgcn_s_barrier() is NOT a compiler
// memory fence, so LDS reads / DMA issues could be moved into the window
// between the vmcnt-wait asm and the barrier, breaking the cross-wave
// residency protocol (intermittent post-timing divergence in round 4).
//
// Per K-tile t (cur buf), 4 phases, staging tile t+1 (nxt buf), 2 chunks
// (64 rows) per phase in order B0,B1 | B2,B3 | A0,A2 | A1,A3:
//   P0: ds A(mh0,k0)+B(k0) | stage B0,B1 | bar | lgkm0 | 16 MFMA | vmcnt(2) bar
//   P1: ds A(mh1,k0)       | stage B2,B3 | bar | lgkm0 | 16 MFMA | bar
//   P2: ds A(mh0,k1)+B(k1) | stage A0,A2 | bar | lgkm0 | 16 MFMA | bar
//   P3: ds A(mh1,k1)       | stage A1,A3 | bar | lgkm0 | 16 MFMA | vmcnt(2) bar
// Residency: vmcnt(2)@P3 leaves only A1,A3(t+1) in flight -> P0 of t+1 needs
// exactly B0-B3,A0,A2 (all older). vmcnt(2)@P0 retires A1,A3 before P1 reads
// them. Waits precede barriers, so guarantees compose across all waves.
// ---------------------------------------------------------------------------
__global__ __launch_bounds__(512, 2) void gemm_8ph(const _Float16* __restrict__ A,
                                                   const _Float16* __restrict__ B,
                                                   float* __restrict__ C) {
    __shared__ _Float16 As[2 * TILE_H];
    __shared__ _Float16 Bs[2 * TILE_H];

    const int tid  = threadIdx.x;
    const int lane = tid & 63;
    const int wave = tid >> 6;
    const int wr = wave >> 2;          // 0..1  (M half)
    const int wc = wave & 3;           // 0..3  (N quarter)

    // XCD-aware bijective block swizzle: nwg = 32*43 = 1376 = 8*172.
    int bid = blockIdx.x;
    int swz = (bid & 7) * 172 + (bid >> 3);
    const int n0 = (swz % 43) * BN2;
    const int m0 = (swz / 43) * BM2;

    // Staging: one chunk = 64 rows x 64 cols (8 KB) = 512 thr x 16 B.
    // Wave w covers rows [chunk*64 + w*8, +8); lane l: row w*8 + (l>>3),
    // 16 B at swizzled-source col ((l&7)*8) ^ ((l>>3)<<3). DMA dest linear.
    const int srow = lane >> 3;
    const int scol = ((lane & 7) * 8) ^ (srow << 3);
    const _Float16* aptr = A + (size_t)(m0 + wave * 8 + srow) * K_DIM + scol;
    const _Float16* bptr = B + (size_t)(n0 + wave * 8 + srow) * K_DIM + scol;

#define STAGE_A8(cbn, c, kof) \
    GLD_LDS16(aptr + (size_t)((c) * 64) * K_DIM + (kof), &As[(cbn) + (c) * 4096 + wave * 512])
#define STAGE_B8(cbn, c, kof) \
    GLD_LDS16(bptr + (size_t)((c) * 64) * K_DIM + (kof), &Bs[(cbn) + (c) * 4096 + wave * 512])

    floatx4 acc[8][4] = {};
    half8 af[4], bf[4];
    const int lrow = lane & 15;
    const int quad = lane >> 4;
    const int kxor = (lrow & 7) << 3;
    const int arow = wr * 128 + lrow;
    const int brow = wc * 64 + lrow;

#define DS_A4(cb, mh, ks)                                                      \
    {                                                                          \
        const int kq = ((ks) * 32 + quad * 8) ^ kxor;                          \
        af[0] = *(const half8*)&As[(cb) + (arow + (mh) * 64 +  0) * 64 + kq];  \
        af[1] = *(const half8*)&As[(cb) + (arow + (mh) * 64 + 16) * 64 + kq];  \
        af[2] = *(const half8*)&As[(cb) + (arow + (mh) * 64 + 32) * 64 + kq];  \
        af[3] = *(const half8*)&As[(cb) + (arow + (mh) * 64 + 48) * 64 + kq];  \
    }
#define DS_B4(cb, ks)                                                          \
    {                                                                          \
        const int kq = ((ks) * 32 + quad * 8) ^ kxor;                          \
        bf[0] = *(const half8*)&Bs[(cb) + (brow +  0) * 64 + kq];              \
        bf[1] = *(const half8*)&Bs[(cb) + (brow + 16) * 64 + kq];              \
        bf[2] = *(const half8*)&Bs[(cb) + (brow + 32) * 64 + kq];              \
        bf[3] = *(const half8*)&Bs[(cb) + (brow + 48) * 64 + kq];              \
    }
#define MFMA16(mh)                                                             \
    _Pragma("unroll")                                                          \
    for (int im = 0; im < 4; ++im)                                             \
        _Pragma("unroll")                                                      \
        for (int in_ = 0; in_ < 4; ++in_)                                      \
            acc[(mh) * 4 + im][in_] = __builtin_amdgcn_mfma_f32_16x16x32_f16(  \
                af[im], bf[in_], acc[(mh) * 4 + im][in_], 0, 0, 0);

// Barrier = HW barrier + compiler memory fence (the race fix).
#define BAR   asm volatile("s_barrier" ::: "memory")
#define WAITL asm volatile("s_waitcnt lgkmcnt(0)" ::: "memory");               \
              __builtin_amdgcn_sched_barrier(0)
#define WVM2  asm volatile("s_waitcnt vmcnt(2)" ::: "memory");                 \
              __builtin_amdgcn_sched_barrier(0)
#define WVM0  asm volatile("s_waitcnt vmcnt(0)" ::: "memory");                 \
              __builtin_amdgcn_sched_barrier(0)
#define PRIO1 __builtin_amdgcn_s_setprio(1)
#define PRIO0 __builtin_amdgcn_s_setprio(0)

    // ---- prologue: stage tile 0 into buf 0, same chunk order as the loop
    STAGE_B8(0, 0, 0); STAGE_B8(0, 1, 0); STAGE_B8(0, 2, 0); STAGE_B8(0, 3, 0);
    STAGE_A8(0, 0, 0); STAGE_A8(0, 2, 0); STAGE_A8(0, 1, 0); STAGE_A8(0, 3, 0);
    WVM2;              // B0-B3, A0, A2 of tile 0 resident; A1,A3 in flight
    BAR;

    int cb = 0;        // LDS half-offset of current buffer (tile t = t&1)
    for (int t = 0; t < NT - 1; ++t) {
        const int cbn = cb ^ TILE_H;
        const size_t kof = (size_t)(t + 1) * BK2;
        // ---- P0
        DS_A4(cb, 0, 0); DS_B4(cb, 0);
        STAGE_B8(cbn, 0, kof); STAGE_B8(cbn, 1, kof);
        BAR; WAITL;
        PRIO1; MFMA16(0); PRIO0;
        WVM2; BAR;     // A1,A3(t) now resident for P1
        // ---- P1
        DS_A4(cb, 1, 0);
        STAGE_B8(cbn, 2, kof); STAGE_B8(cbn, 3, kof);
        BAR; WAITL;
        PRIO1; MFMA16(1); PRIO0;
        BAR;
        // ---- P2
        DS_A4(cb, 0, 1); DS_B4(cb, 1);
        STAGE_A8(cbn, 0, kof); STAGE_A8(cbn, 2, kof);
        BAR; WAITL;
        PRIO1; MFMA16(0); PRIO0;
        BAR;
        // ---- P3
        DS_A4(cb, 1, 1);
        STAGE_A8(cbn, 1, kof); STAGE_A8(cbn, 3, kof);
        BAR; WAITL;
        PRIO1; MFMA16(1); PRIO0;
        WVM2; BAR;     // everything except A1,A3(t+1) resident for next P0
        cb = cbn;
    }

    // ---- epilogue tile NT-1 (in buf cb), no staging
    DS_A4(cb, 0, 0); DS_B4(cb, 0);
    WAITL; PRIO1; MFMA16(0); PRIO0;
    WVM0; BAR;         // A1,A3 of last tile resident (all waves)
    DS_A4(cb, 1, 0);
    WAITL; PRIO1; MFMA16(1); PRIO0;
    DS_A4(cb, 0, 1); DS_B4(cb, 1);
    WAITL; PRIO1; MFMA16(0); PRIO0;
    DS_A4(cb, 1, 1);
    WAITL; PRIO1; MFMA16(1); PRIO0;

    // ---- C write: C/D layout col=lane&15, row=(lane>>4)*4+reg
#pragma unroll
    for (int mf = 0; mf < 8; ++mf) {
#pragma unroll
        for (int in_ = 0; in_ < 4; ++in_) {
            int col = n0 + wc * 64 + in_ * 16 + lrow;
#pragma unroll
            for (int r = 0; r < 4; ++r) {
                int row = m0 + wr * 128 + mf * 16 + quad * 4 + r;
                C[(size_t)row * N_DIM + col] = acc[mf][in_][r];
            }
        }
    }
}

// ---------------------------------------------------------------------------
// Mid path (ws fits deq only): explicit-staging 128^2 GEMM (round-1 version).
// ---------------------------------------------------------------------------
__global__ __launch_bounds__(256, 2) void gemm_f16_bt(const float* __restrict__ A,
                                                      const _Float16* __restrict__ B,
                                                      float* __restrict__ C) {
    __shared__ _Float16 As[BM * BK];
    __shared__ _Float16 Bs[BN * BK];

    const int tid  = threadIdx.x;
    const int lane = tid & 63;
    const int wave = tid >> 6;
    const int wm = (wave >> 1) * 64;
    const int wn = (wave & 1) * 64;
    const int m0 = blockIdx.y * BM;
    const int n0 = blockIdx.x * BN;

    floatx4 acc[4][4] = {};
    const int lrow = lane & 15;
    const int quad = lane >> 4;
    const int kxor = (lrow & 7) << 3;

    for (int kk = 0; kk < K_DIM; kk += BK) {
        float4 av[8];
#pragma unroll
        for (int i = 0; i < 8; ++i) {
            int flat = i * 256 + tid;
            int row = flat >> 4;
            int col = (flat & 15) * 4;
            av[i] = *(const float4*)(A + (size_t)(m0 + row) * K_DIM + kk + col);
        }
        half8 bv[4];
#pragma unroll
        for (int i = 0; i < 4; ++i) {
            int flat = i * 256 + tid;
            int row = flat >> 3;
            int col = (flat & 7) * 8;
            bv[i] = *(const half8*)(B + (size_t)(n0 + row) * K_DIM + kk + col);
        }
        __syncthreads();
#pragma unroll
        for (int i = 0; i < 8; ++i) {
            int flat = i * 256 + tid;
            int row = flat >> 4;
            int col = (flat & 15) * 4;
            half4 a16;
            a16[0] = (_Float16)av[i].x;
            a16[1] = (_Float16)av[i].y;
            a16[2] = (_Float16)av[i].z;
            a16[3] = (_Float16)av[i].w;
            *(half4*)(As + row * BK + SWZ(row, col)) = a16;
        }
#pragma unroll
        for (int i = 0; i < 4; ++i) {
            int flat = i * 256 + tid;
            int row = flat >> 3;
            int col = (flat & 7) * 8;
            *(half8*)(Bs + row * BK + SWZ(row, col)) = bv[i];
        }
        __syncthreads();

#pragma unroll
        for (int ks = 0; ks < BK; ks += 32) {
            int koff = (ks + quad * 8) ^ kxor;
            half8 af[4], bf[4];
#pragma unroll
            for (int im = 0; im < 4; ++im)
                af[im] = *(const half8*)(As + (wm + im * 16 + lrow) * BK + koff);
#pragma unroll
            for (int in_ = 0; in_ < 4; ++in_)
                bf[in_] = *(const half8*)(Bs + (wn + in_ * 16 + lrow) * BK + koff);
#pragma unroll
            for (int im = 0; im < 4; ++im)
#pragma unroll
                for (int in_ = 0; in_ < 4; ++in_)
                    acc[im][in_] = __builtin_amdgcn_mfma_f32_16x16x32_f16(
                        af[im], bf[in_], acc[im][in_], 0, 0, 0);
        }
    }

#pragma unroll
    for (int im = 0; im < 4; ++im) {
#pragma unroll
        for (int in_ = 0; in_ < 4; ++in_) {
            int col = n0 + wn + in_ * 16 + lrow;
#pragma unroll
            for (int r = 0; r < 4; ++r) {
                int row = m0 + wm + im * 16 + quad * 4 + r;
                C[(size_t)row * N_DIM + col] = acc[im][in_][r];
            }
        }
    }
}

// ---------------------------------------------------------------------------
// Fallback: fused dequant-in-GEMM (only if ws too small for any prepass).
// ---------------------------------------------------------------------------
__global__ __launch_bounds__(256, 2) void gemm_fused(const float* __restrict__ A,
                                                     const int* __restrict__ W,
                                                     const float* __restrict__ S,
                                                     float* __restrict__ C) {
    __shared__ _Float16 As[BM * BK];
    __shared__ _Float16 Bs[BN * BK];

    const int tid  = threadIdx.x;
    const int lane = tid & 63;
    const int wave = tid >> 6;
    const int wm = (wave >> 1) * 64;
    const int wn = (wave & 1) * 64;
    const int m0 = blockIdx.y * BM;
    const int n0 = blockIdx.x * BN;

    floatx4 acc[4][4] = {};
    const int lrow = lane & 15;
    const int quad = lane >> 4;
    const int kxor = (lrow & 7) << 3;

    const int nn = tid >> 1;
    const int bh = (tid & 1) * 32;

    for (int kk = 0; kk < K_DIM; kk += BK) {
        float4 av[8];
#pragma unroll
        for (int i = 0; i < 8; ++i) {
            int flat = i * 256 + tid;
            int row = flat >> 4;
            int col = (flat & 15) * 4;
            av[i] = *(const float4*)(A + (size_t)(m0 + row) * K_DIM + kk + col);
        }
        int t64 = kk >> 6;
        int u = t64 >> 1;
        const int* wr = W + ((size_t)(n0 + nn) * 32 + u) * 64 + bh;
        float sc = S[(size_t)(n0 + nn) * 64 + t64];
        bool sel_lsb = (t64 & 1);
        half8 bq[4];
#pragma unroll
        for (int i8 = 0; i8 < 4; ++i8) {
            int4 pa = *(const int4*)(wr + i8 * 8);
            int4 pb = *(const int4*)(wr + i8 * 8 + 4);
            int vv[8] = {pa.x, pa.y, pa.z, pa.w, pb.x, pb.y, pb.z, pb.w};
#pragma unroll
            for (int q = 0; q < 8; ++q) {
                int b = vv[q];
                int qq = sel_lsb ? ((b << 28) >> 28) : (b >> 4);
                bq[i8][q] = (_Float16)((float)qq * sc);
            }
        }
        __syncthreads();
#pragma unroll
        for (int i = 0; i < 8; ++i) {
            int flat = i * 256 + tid;
            int row = flat >> 4;
            int col = (flat & 15) * 4;
            half4 a16;
            a16[0] = (_Float16)av[i].x;
            a16[1] = (_Float16)av[i].y;
            a16[2] = (_Float16)av[i].z;
            a16[3] = (_Float16)av[i].w;
            *(half4*)(As + row * BK + SWZ(row, col)) = a16;
        }
#pragma unroll
        for (int i8 = 0; i8 < 4; ++i8)
            *(half8*)(Bs + nn * BK + SWZ(nn, bh + i8 * 8)) = bq[i8];
        __syncthreads();

#pragma unroll
        for (int ks = 0; ks < BK; ks += 32) {
            int koff = (ks + quad * 8) ^ kxor;
            half8 af[4], bf[4];
#pragma unroll
            for (int im = 0; im < 4; ++im)
                af[im] = *(const half8*)(As + (wm + im * 16 + lrow) * BK + koff);
#pragma unroll
            for (int in_ = 0; in_ < 4; ++in_)
                bf[in_] = *(const half8*)(Bs + (wn + in_ * 16 + lrow) * BK + koff);
#pragma unroll
            for (int im = 0; im < 4; ++im)
#pragma unroll
                for (int in_ = 0; in_ < 4; ++in_)
                    acc[im][in_] = __builtin_amdgcn_mfma_f32_16x16x32_f16(
                        af[im], bf[in_], acc[im][in_], 0, 0, 0);
        }
    }

#pragma unroll
    for (int im = 0; im < 4; ++im) {
#pragma unroll
        for (int in_ = 0; in_ < 4; ++in_) {
            int col = n0 + wn + in_ * 16 + lrow;
#pragma unroll
            for (int r = 0; r < 4; ++r) {
                int row = m0 + wm + im * 16 + quad * 4 + r;
                C[(size_t)row * N_DIM + col] = acc[im][in_][r];
            }
        }
    }
}

extern "C" void kernel_launch(void* const* d_in, const int* in_sizes, int n_in,
                              void* d_out, int out_size, void* d_ws, size_t ws_size,
                              hipStream_t stream) {
    const float* x = (const float*)d_in[0];   // fp16 upcast to fp32 by harness
    const int*   w = (const int*)d_in[1];     // int8 widened to int32
    const float* s = (const float*)d_in[2];   // fp16 upcast to fp32
    float*     out = (float*)d_out;           // fp32

    const size_t deq_bytes = (size_t)N_DIM * K_DIM * sizeof(_Float16); // 90.2 MB
    const size_t a16_bytes = (size_t)M_DIM * K_DIM * sizeof(_Float16); // 67.1 MB

    if (ws_size >= deq_bytes + a16_bytes) {
        _Float16* deq = (_Float16*)d_ws;
        _Float16* a16 = (_Float16*)((char*)d_ws + deq_bytes);
        dequant_q40<<<11008, 256, 0, stream>>>(w, s, deq);
        conv_a16<<<(M_DIM * K_DIM / 8) / 256, 256, 0, stream>>>(x, a16);
        gemm_8ph<<<(M_DIM / BM2) * (N_DIM / BN2), 512, 0, stream>>>(a16, deq, out);
    } else if (ws_size >= deq_bytes) {
        _Float16* deq = (_Float16*)d_ws;
        dim3 grid(N_DIM / BN, M_DIM / BM);
        dequant_q40<<<11008, 256, 0, stream>>>(w, s, deq);
        gemm_f16_bt<<<grid, 256, 0, stream>>>(x, deq, out);
    } else {
        dim3 grid(N_DIM / BN, M_DIM / BM);
        gemm_fused<<<grid, 256, 0, stream>>>(x, w, s, out);
    }
}